// Round 10
// baseline (1011.210 us; speedup 1.0000x reference)
//
#include <hip/hip_runtime.h>
#include <stdint.h>

// ---- Problem constants -------------------------------------------------
#define DIM   1536
#define NQ    6272      // 8 * 28 * 28 queries
#define NQP   6400      // padded to 25 * 256
#define NB    50000     // bank rows
#define NBP2  50176     // padded to 196 * 256
#define MT2   25
#define NT2   196
#define GRID2 (MT2 * NT2)
#define NKT   24        // 1536 / 64 K-tiles
#define NIT   12        // NKT / 2 iterations
#define NPIX  (8 * 224 * 224)

typedef __bf16 bf16x8 __attribute__((ext_vector_type(8)));
typedef float  f32x4  __attribute__((ext_vector_type(4)));
typedef __attribute__((address_space(3))) unsigned short lds_us;

__device__ inline unsigned short f2bf(float f) {
  uint32_t u = __float_as_uint(f);
  u += 0x7FFFu + ((u >> 16) & 1u);   // RNE
  return (unsigned short)(u >> 16);
}

__device__ inline void gll16(const unsigned short* g, unsigned short* l) {
  __builtin_amdgcn_global_load_lds(
      (const __attribute__((address_space(1))) uint32_t*)g,
      (__attribute__((address_space(3))) uint32_t*)l, 16, 0, 0);
}

// ---- init: minbits = +inf, image scores = 0 ---------------------------
__global__ void init_kernel(uint32_t* __restrict__ minbits, float* __restrict__ out_scores) {
  int i = blockIdx.x * 256 + threadIdx.x;
  if (i < NQP) minbits[i] = 0x7F800000u;   // +inf
  if (i < 8)   out_scores[i] = 0.0f;
}

// ---- fp32 -> bf16 row conversion + fp32 row norms ---------------------
__global__ void conv_rows(const float* __restrict__ src, unsigned short* __restrict__ dst,
                          float* __restrict__ norms, int nsrc, int ndst) {
  int row  = blockIdx.x * 4 + (threadIdx.x >> 6);
  int lane = threadIdx.x & 63;
  if (row >= ndst) return;
  unsigned short* drow = dst + (size_t)row * DIM;
  if (row < nsrc) {
    const float4* s = (const float4*)(src + (size_t)row * DIM);
    float ns = 0.f;
#pragma unroll
    for (int i = 0; i < 6; ++i) {
      float4 v = s[lane + 64 * i];
      ns += v.x * v.x + v.y * v.y + v.z * v.z + v.w * v.w;
      ushort4 o;
      o.x = f2bf(v.x); o.y = f2bf(v.y); o.z = f2bf(v.z); o.w = f2bf(v.w);
      *(ushort4*)(drow + (lane + 64 * i) * 4) = o;
    }
#pragma unroll
    for (int off = 32; off >= 1; off >>= 1) ns += __shfl_xor(ns, off);
    if (lane == 0) norms[row] = ns;
  } else {
    ushort4 z = {0, 0, 0, 0};
#pragma unroll
    for (int i = 0; i < 6; ++i) *(ushort4*)(drow + (lane + 64 * i) * 4) = z;
    if (lane == 0) norms[row] = 1e30f;   // pad rows never win the min
  }
}

// ---- fused 256x256 8-phase GEMM + column-min --------------------------
// BM=BN=256, BK=64, 512 thr = 8 waves (2M x 4N), per-wave 128x64 out.
// m201-faithful skeleton: {reads; stages; [vmcnt gate]; BAR; lgkmcnt(0);
// setprio; 16 MFMA; setprio; BAR}. Read service overlaps barrier wait;
// counted vmcnt(4) only at ph4/ph8 (covered loads >=3 phases old).
#define BAR   asm volatile("s_barrier" ::: "memory")
#define LGKM0 do { asm volatile("s_waitcnt lgkmcnt(0)" ::: "memory"); \
                   __builtin_amdgcn_sched_barrier(0); } while(0)
#define VM4   asm volatile("s_waitcnt vmcnt(4)" ::: "memory")
#define VM0   asm volatile("s_waitcnt vmcnt(0)" ::: "memory")
#define PHI   __builtin_amdgcn_s_setprio(1)
#define PLO   __builtin_amdgcn_s_setprio(0)

// ds_read_b128 with base VGPR + compile-time immediate offset (zero VALU)
#define DSR(dst, base, imm) \
  asm volatile("ds_read_b128 %0, %1 offset:%2" : "=v"(dst) : "v"(base), "i"(imm))

// A frag quad (rows (half*4+m)*16+lr of sA[buf][wm]); bytes: buf*32768+half*8192+m*2048
#define READ_A4A(dst, bufI, half, kk) do { \
  DSR(dst[0], ((kk) ? aOffO : aOffE), (bufI) * 32768 + (half) * 8192 + 0);    \
  DSR(dst[1], ((kk) ? aOffO : aOffE), (bufI) * 32768 + (half) * 8192 + 2048); \
  DSR(dst[2], ((kk) ? aOffO : aOffE), (bufI) * 32768 + (half) * 8192 + 4096); \
  DSR(dst[3], ((kk) ? aOffO : aOffE), (bufI) * 32768 + (half) * 8192 + 6144); \
} while(0)

// B frag quad (rows bq*64+n*16+lr of sB[buf][bh]); bytes: buf*32768+n*2048
#define READ_B4A(dst, bufI, kk) do { \
  DSR(dst[0], ((kk) ? bOffO : bOffE), (bufI) * 32768 + 0);    \
  DSR(dst[1], ((kk) ? bOffO : bOffE), (bufI) * 32768 + 2048); \
  DSR(dst[2], ((kk) ? bOffO : bOffE), (bufI) * 32768 + 4096); \
  DSR(dst[3], ((kk) ? bOffO : bOffE), (bufI) * 32768 + 6144); \
} while(0)

#define MFMA16(half, a4, b4) do { \
  _Pragma("unroll") for (int m_ = 0; m_ < 4; ++m_) \
  _Pragma("unroll") for (int n_ = 0; n_ < 4; ++n_) \
    acc[(half) * 4 + m_][n_] = __builtin_amdgcn_mfma_f32_16x16x32_bf16( \
      __builtin_bit_cast(bf16x8, a4[m_]), __builtin_bit_cast(bf16x8, b4[n_]), \
      acc[(half) * 4 + m_][n_], 0, 0, 0); \
} while(0)

#define STAGE_A(bufI, hI, ktc) do { \
  const unsigned short* _g = gA + (size_t)((hI) * 128 + srow) * DIM + (ktc) + scol; \
  gll16(_g,                     &sA[bufI][hI][sdst]); \
  gll16(_g + (size_t)64 * DIM,  &sA[bufI][hI][4096 + sdst]); \
} while(0)

#define STAGE_B(bufI, hI, ktc) do { \
  const unsigned short* _g = gB + (size_t)((hI) * 128 + srow) * DIM + (ktc) + scol; \
  gll16(_g,                     &sB[bufI][hI][sdst]); \
  gll16(_g + (size_t)64 * DIM,  &sB[bufI][hI][4096 + sdst]); \
} while(0)

// iter i: tiles 2i (buf0, ph1-4) + 2i+1 (buf1, ph5-8). Reads feed the SAME
// phase's MFMA (drained post-barrier). Stages: ph1 A1 [tile 2i+1, region
// free: last read prev-ph8 + LGKM0 + BAR2], ph4 B0', ph5 A0' [tile 2i+2],
// ph8 B1' [tile 2i+3] -- each 1 full phase after its region's last reader.
// Gates: ph4 vmcnt(4) retires {B1 prev-ph8, A1 ph1} keeping B0' in flight
// (buf1 read from ph5); ph8 vmcnt(4) retires {B0', A0'} keeping B1'
// (buf0' read from next ph1). Tail: VM0 at ph4, none needed at ph8.
#define ITER(T0, SN) do { \
  /* ph1 */ READ_A4A(a4, 0, 0, 0); READ_B4A(bk, 0, 0); \
    STAGE_A(1, 0, (T0) + 64); STAGE_A(1, 1, (T0) + 64); \
    BAR; LGKM0; PHI; MFMA16(0, a4, bk); PLO; BAR; \
  /* ph2 */ READ_A4A(a4, 0, 1, 0); \
    BAR; LGKM0; PHI; MFMA16(1, a4, bk); PLO; BAR; \
  /* ph3 */ READ_A4A(a4, 0, 0, 1); READ_B4A(bk, 0, 1); \
    BAR; LGKM0; PHI; MFMA16(0, a4, bk); PLO; BAR; \
  /* ph4 */ READ_A4A(a4, 0, 1, 1); \
    if (SN) { STAGE_B(0, 0, (T0) + 128); STAGE_B(0, 1, (T0) + 128); VM4; } \
    else    { VM0; } \
    BAR; LGKM0; PHI; MFMA16(1, a4, bk); PLO; BAR; \
  /* ph5 */ READ_A4A(a4, 1, 0, 0); READ_B4A(bk, 1, 0); \
    if (SN) { STAGE_A(0, 0, (T0) + 128); STAGE_A(0, 1, (T0) + 128); } \
    BAR; LGKM0; PHI; MFMA16(0, a4, bk); PLO; BAR; \
  /* ph6 */ READ_A4A(a4, 1, 1, 0); \
    BAR; LGKM0; PHI; MFMA16(1, a4, bk); PLO; BAR; \
  /* ph7 */ READ_A4A(a4, 1, 0, 1); READ_B4A(bk, 1, 1); \
    BAR; LGKM0; PHI; MFMA16(0, a4, bk); PLO; BAR; \
  /* ph8 */ READ_A4A(a4, 1, 1, 1); \
    if (SN) { STAGE_B(1, 0, (T0) + 192); STAGE_B(1, 1, (T0) + 192); VM4; } \
    BAR; LGKM0; PHI; MFMA16(1, a4, bk); PLO; BAR; \
} while(0)

__global__ __launch_bounds__(512, 2)
void gemm_min8(const unsigned short* __restrict__ fA, const unsigned short* __restrict__ bB,
               const float* __restrict__ bn, uint32_t* __restrict__ minbits) {
  __shared__ unsigned short sA[2][2][8192];   // 64 KiB
  __shared__ unsigned short sB[2][2][8192];   // 64 KiB

  const int nwg = GRID2;
  int bid = blockIdx.x;
  const int qch = nwg >> 3, rch = nwg & 7;
  int xcd = bid & 7, loc = bid >> 3;
  int swz = (xcd < rch ? xcd * (qch + 1) : rch * (qch + 1) + (xcd - rch) * qch) + loc;
  int mt = swz % MT2;            // M-fast: consecutive blocks share the B (bank) panel
  int nt = swz / MT2;

  int tid = threadIdx.x;
  int lane = tid & 63, wave = tid >> 6;
  int wm = wave >> 2, wn = wave & 3, bq = wn & 1, bh = wn >> 1;
  int lr = lane & 15, lk8 = (lane >> 4) * 8;
  int lswz = (lane & 7) << 3;    // XOR on 16B-slot bits (ushort units)

  const unsigned short* gA = fA + (size_t)(mt * 256) * DIM;
  const unsigned short* gB = bB + (size_t)(nt * 256) * DIM;

  int srow = tid >> 3;                                    // 0..63
  int scol = ((tid & 7) * 8) ^ (((tid >> 3) & 7) << 3);   // pre-swizzled source col (bf16)
  int sdst = tid * 8;                                     // linear LDS dest (ushort)

  // 32-bit LDS byte-offset bases for asm ds_read (E: kk=0, O: kk=1)
  uint32_t aOffE = (uint32_t)(uintptr_t)(lds_us*)&sA[0][wm][lr * 64 + (lk8 ^ lswz)];
  uint32_t aOffO = (uint32_t)(uintptr_t)(lds_us*)&sA[0][wm][lr * 64 + ((32 + lk8) ^ lswz)];
  uint32_t bOffE = (uint32_t)(uintptr_t)(lds_us*)&sB[0][bh][(bq * 64 + lr) * 64 + (lk8 ^ lswz)];
  uint32_t bOffO = (uint32_t)(uintptr_t)(lds_us*)&sB[0][bh][(bq * 64 + lr) * 64 + ((32 + lk8) ^ lswz)];

  f32x4 acc[8][4] = {};
  f32x4 a4[4], bk[4];

  // prologue: tile0 (A0,B0) + tile1 B (B1) staged; retire A0+B0 (VM4 keeps
  // B1 in flight -- first needed at ph5, covered by ph4's gate), publish.
  STAGE_A(0, 0, 0); STAGE_A(0, 1, 0);
  STAGE_B(0, 0, 0); STAGE_B(0, 1, 0);
  STAGE_B(1, 0, 64); STAGE_B(1, 1, 64);
  VM4; BAR;

#pragma unroll 1
  for (int i = 0; i < NIT - 1; ++i) {
    ITER(i * 128, 1);
  }
  ITER((NIT - 1) * 128, 0);   // tiles 22,23: no next-tile stages; VM0 at ph4

  // epilogue: per-row min over this tile's 256 columns of (bn - 2*dot)
  float bnv[4];
#pragma unroll
  for (int n_ = 0; n_ < 4; ++n_)
    bnv[n_] = bn[nt * 256 + wn * 64 + n_ * 16 + lr];
  int qbase = mt * 256 + wm * 128;
#pragma unroll
  for (int m_ = 0; m_ < 8; ++m_) {
#pragma unroll
    for (int r = 0; r < 4; ++r) {
      float v = bnv[0] - 2.0f * acc[m_][0][r];
      v = fminf(v, bnv[1] - 2.0f * acc[m_][1][r]);
      v = fminf(v, bnv[2] - 2.0f * acc[m_][2][r]);
      v = fminf(v, bnv[3] - 2.0f * acc[m_][3][r]);
      // C/D layout: col = lane&15, row = (lane>>4)*4 + r
      v = fminf(v, __shfl_xor(v, 1));
      v = fminf(v, __shfl_xor(v, 2));
      v = fminf(v, __shfl_xor(v, 4));
      v = fminf(v, __shfl_xor(v, 8));
      if (lr == 0) {
        int q = qbase + m_ * 16 + (lane >> 4) * 4 + r;
        atomicMin(&minbits[q], __float_as_uint(v));  // positive floats: uint order == float order
      }
    }
  }
}

// ---- patch scores + per-image max -------------------------------------
__global__ void scores_kernel(const uint32_t* __restrict__ minbits, const float* __restrict__ qn,
                              float* __restrict__ ps, float* __restrict__ img) {
  int q = blockIdx.x * 256 + threadIdx.x;
  if (q >= NQ) return;
  float s = __uint_as_float(minbits[q]) + qn[q];
  ps[q] = s;
  atomicMax((uint32_t*)&img[q / 784], __float_as_uint(s));  // scores > 0
}

// ---- bilinear 28x28 -> 224x224 (half-pixel centers, edge clamp) -------
__global__ void resize_kernel(const float* __restrict__ ps, float* __restrict__ masks) {
  int idx = blockIdx.x * 256 + threadIdx.x;
  if (idx >= NPIX) return;
  int b   = idx / (224 * 224);
  int rem = idx - b * (224 * 224);
  int oy  = rem / 224;
  int ox  = rem - oy * 224;
  float sy = (oy + 0.5f) * 0.125f - 0.5f;
  float sx = (ox + 0.5f) * 0.125f - 0.5f;
  float fy0 = floorf(sy), fx0 = floorf(sx);
  int y0 = (int)fy0, x0 = (int)fx0;
  float fy = sy - fy0, fx = sx - fx0;
  int y0c = min(max(y0, 0), 27),     y1c = min(max(y0 + 1, 0), 27);
  int x0c = min(max(x0, 0), 27),     x1c = min(max(x0 + 1, 0), 27);
  const float* p = ps + b * 784;
  float top = p[y0c * 28 + x0c] * (1.f - fx) + p[y0c * 28 + x1c] * fx;
  float bot = p[y1c * 28 + x0c] * (1.f - fx) + p[y1c * 28 + x1c] * fx;
  masks[idx] = top * (1.f - fy) + bot * fy;
}

// ---- host launch -------------------------------------------------------
extern "C" void kernel_launch(void* const* d_in, const int* in_sizes, int n_in,
                              void* d_out, int out_size, void* d_ws, size_t ws_size,
                              hipStream_t stream) {
  const float* features = (const float*)d_in[0];   // [6272, 1536]
  const float* bank     = (const float*)d_in[1];   // [50000, 1536]

  char* ws = (char*)d_ws;
  size_t off = 0;
  unsigned short* bankB = (unsigned short*)(ws + off); off += (size_t)NBP2 * DIM * 2;  // 154.1 MB
  unsigned short* featB = (unsigned short*)(ws + off); off += (size_t)NQP * DIM * 2;   // 19.7 MB
  float*    bn      = (float*)(ws + off);    off += (size_t)NBP2 * 4;
  float*    qn      = (float*)(ws + off);    off += (size_t)NQP * 4;
  uint32_t* minbits = (uint32_t*)(ws + off); off += (size_t)NQP * 4;
  float*    ps      = (float*)(ws + off);    off += (size_t)NQ * 4;

  float* out_scores = (float*)d_out;       // [8]
  float* masks      = out_scores + 8;      // [8,224,224]

  hipLaunchKernelGGL(init_kernel, dim3(25), dim3(256), 0, stream, minbits, out_scores);
  hipLaunchKernelGGL(conv_rows, dim3(NBP2 / 4), dim3(256), 0, stream, bank, bankB, bn, NB, NBP2);
  hipLaunchKernelGGL(conv_rows, dim3(NQP / 4), dim3(256), 0, stream, features, featB, qn, NQ, NQP);
  hipLaunchKernelGGL(gemm_min8, dim3(GRID2), dim3(512), 0, stream, featB, bankB, bn, minbits);
  hipLaunchKernelGGL(scores_kernel, dim3(25), dim3(256), 0, stream, minbits, qn, ps, out_scores);
  hipLaunchKernelGGL(resize_kernel, dim3((NPIX + 255) / 256), dim3(256), 0, stream, ps, masks);
}

// Round 12
// 956.873 us; speedup vs baseline: 1.0568x; 1.0568x over previous
//
#include <hip/hip_runtime.h>
#include <stdint.h>

// ---- Problem constants -------------------------------------------------
#define DIM   1536
#define NQ    6272      // 8 * 28 * 28 queries
#define NQP   6400      // padded to 25 * 256
#define NB    50000     // bank rows
#define NBP2  50176     // padded to 196 * 256
#define MT2   25
#define NT2   196
#define GRID2 (MT2 * NT2)
#define NKT   24        // 1536 / 64 K-tiles
#define NIT   12        // NKT / 2 iterations
#define NPIX  (8 * 224 * 224)

typedef __bf16 bf16x8 __attribute__((ext_vector_type(8)));
typedef float  f32x4  __attribute__((ext_vector_type(4)));
typedef __attribute__((address_space(3))) unsigned short lds_us;

__device__ inline unsigned short f2bf(float f) {
  uint32_t u = __float_as_uint(f);
  u += 0x7FFFu + ((u >> 16) & 1u);   // RNE
  return (unsigned short)(u >> 16);
}

__device__ inline void gll16(const unsigned short* g, unsigned short* l) {
  __builtin_amdgcn_global_load_lds(
      (const __attribute__((address_space(1))) uint32_t*)g,
      (__attribute__((address_space(3))) uint32_t*)l, 16, 0, 0);
}

// ---- init: minbits = +inf, image scores = 0 ---------------------------
__global__ void init_kernel(uint32_t* __restrict__ minbits, float* __restrict__ out_scores) {
  int i = blockIdx.x * 256 + threadIdx.x;
  if (i < NQP) minbits[i] = 0x7F800000u;   // +inf
  if (i < 8)   out_scores[i] = 0.0f;
}

// ---- fp32 -> bf16 row conversion + fp32 row norms ---------------------
__global__ void conv_rows(const float* __restrict__ src, unsigned short* __restrict__ dst,
                          float* __restrict__ norms, int nsrc, int ndst) {
  int row  = blockIdx.x * 4 + (threadIdx.x >> 6);
  int lane = threadIdx.x & 63;
  if (row >= ndst) return;
  unsigned short* drow = dst + (size_t)row * DIM;
  if (row < nsrc) {
    const float4* s = (const float4*)(src + (size_t)row * DIM);
    float ns = 0.f;
#pragma unroll
    for (int i = 0; i < 6; ++i) {
      float4 v = s[lane + 64 * i];
      ns += v.x * v.x + v.y * v.y + v.z * v.z + v.w * v.w;
      ushort4 o;
      o.x = f2bf(v.x); o.y = f2bf(v.y); o.z = f2bf(v.z); o.w = f2bf(v.w);
      *(ushort4*)(drow + (lane + 64 * i) * 4) = o;
    }
#pragma unroll
    for (int off = 32; off >= 1; off >>= 1) ns += __shfl_xor(ns, off);
    if (lane == 0) norms[row] = ns;
  } else {
    ushort4 z = {0, 0, 0, 0};
#pragma unroll
    for (int i = 0; i < 6; ++i) *(ushort4*)(drow + (lane + 64 * i) * 4) = z;
    if (lane == 0) norms[row] = 1e30f;   // pad rows never win the min
  }
}

// ---- fused 256x256 8-phase GEMM + column-min --------------------------
// BM=BN=256, BK=64, 512 thr = 8 waves (2M x 4N), per-wave 128x64 out.
// Counted-lgkm pipeline (R9, verified): phase P issues asm ds_reads for
// P+1 right AFTER a barrier (whose preceding gate covered the staged data),
// stages, waits lgkmcnt(n=just-issued) (drains only P's frags), barrier,
// then MFMA(P) runs while P+1's reads are serviced by the LDS pipe.
#define BAR   asm volatile("s_barrier" ::: "memory")
#define LGKM(n) do { asm volatile("s_waitcnt lgkmcnt(" #n ")" ::: "memory"); \
                     __builtin_amdgcn_sched_barrier(0); } while(0)
#define VM0   asm volatile("s_waitcnt vmcnt(0)" ::: "memory")
#define VM4   asm volatile("s_waitcnt vmcnt(4)" ::: "memory")
#define PHI   __builtin_amdgcn_s_setprio(1)
#define PLO   __builtin_amdgcn_s_setprio(0)

// ds_read_b128 with base VGPR + compile-time immediate offset (zero VALU)
#define DSR(dst, base, imm) \
  asm volatile("ds_read_b128 %0, %1 offset:%2" : "=v"(dst) : "v"(base), "i"(imm))

// A frag quad (rows (half*4+m)*16+lr of sA[buf][wm]); bytes: buf*32768+half*8192+m*2048
#define READ_A4A(dst, bufI, half, kk) do { \
  DSR(dst[0], ((kk) ? aOffO : aOffE), (bufI) * 32768 + (half) * 8192 + 0);    \
  DSR(dst[1], ((kk) ? aOffO : aOffE), (bufI) * 32768 + (half) * 8192 + 2048); \
  DSR(dst[2], ((kk) ? aOffO : aOffE), (bufI) * 32768 + (half) * 8192 + 4096); \
  DSR(dst[3], ((kk) ? aOffO : aOffE), (bufI) * 32768 + (half) * 8192 + 6144); \
} while(0)

// B frag quad (rows bq*64+n*16+lr of sB[buf][bh]); bytes: buf*32768+n*2048
#define READ_B4A(dst, bufI, kk) do { \
  DSR(dst[0], ((kk) ? bOffO : bOffE), (bufI) * 32768 + 0);    \
  DSR(dst[1], ((kk) ? bOffO : bOffE), (bufI) * 32768 + 2048); \
  DSR(dst[2], ((kk) ? bOffO : bOffE), (bufI) * 32768 + 4096); \
  DSR(dst[3], ((kk) ? bOffO : bOffE), (bufI) * 32768 + 6144); \
} while(0)

#define MFMA16(half, a4, b4) do { \
  _Pragma("unroll") for (int m_ = 0; m_ < 4; ++m_) \
  _Pragma("unroll") for (int n_ = 0; n_ < 4; ++n_) \
    acc[(half) * 4 + m_][n_] = __builtin_amdgcn_mfma_f32_16x16x32_bf16( \
      __builtin_bit_cast(bf16x8, a4[m_]), __builtin_bit_cast(bf16x8, b4[n_]), \
      acc[(half) * 4 + m_][n_], 0, 0, 0); \
} while(0)

#define STAGE_A(bufI, hI, ktc) do { \
  const unsigned short* _g = gA + (size_t)((hI) * 128 + srow) * DIM + (ktc) + scol; \
  gll16(_g,                     &sA[bufI][hI][sdst]); \
  gll16(_g + (size_t)64 * DIM,  &sA[bufI][hI][4096 + sdst]); \
} while(0)

#define STAGE_B(bufI, hI, ktc) do { \
  const unsigned short* _g = gB + (size_t)((hI) * 128 + srow) * DIM + (ktc) + scol; \
  gll16(_g,                     &sB[bufI][hI][sdst]); \
  gll16(_g + (size_t)64 * DIM,  &sB[bufI][hI][4096 + sdst]); \
} while(0)

// iter i: MFMA tiles 2i (buf0, ph1-4) + 2i+1 (buf1, ph5-8); reads 1 phase
// ahead (banks aX/aY, bE/bO). Stages: ph1 A(1) [tile 2i+1], ph4 B(0)',
// ph5 A(0)' [tile 2i+2], ph8 B(1)' [tile 2i+3]. Gates: VM0 at ph3 (covers
// ph8'+ph1 stages; buf1 published for ph4 reads) and ph7 (covers ph4+ph5;
// buf0' published for ph8 reads). All reads post-barrier => publish-safe.
// Every stage >=1 barrier after its region's reads drained (WAR-safe).
#define ITER(T0, SN, RD) do { \
  /* ph1: rd A(0,h1,k0) */ READ_A4A(aY, 0, 1, 0); \
    STAGE_A(1, 0, (T0) + 64); STAGE_A(1, 1, (T0) + 64); \
    LGKM(4); BAR; PHI; MFMA16(0, aX, bE); PLO; \
  /* ph2: rd A(0,h0,k1)+B(0,k1) */ READ_A4A(aX, 0, 0, 1); READ_B4A(bO, 0, 1); \
    LGKM(8); BAR; PHI; MFMA16(1, aY, bE); PLO; \
  /* ph3: rd A(0,h1,k1) */ READ_A4A(aY, 0, 1, 1); \
    LGKM(4); VM0; BAR; PHI; MFMA16(0, aX, bO); PLO; \
  /* ph4: rd A(1,h0,k0)+B(1,k0) */ READ_A4A(aX, 1, 0, 0); READ_B4A(bE, 1, 0); \
    if (SN) { STAGE_B(0, 0, (T0) + 128); STAGE_B(0, 1, (T0) + 128); } \
    LGKM(8); BAR; PHI; MFMA16(1, aY, bO); PLO; \
  /* ph5: rd A(1,h1,k0) */ READ_A4A(aY, 1, 1, 0); \
    if (SN) { STAGE_A(0, 0, (T0) + 128); STAGE_A(0, 1, (T0) + 128); } \
    LGKM(4); BAR; PHI; MFMA16(0, aX, bE); PLO; \
  /* ph6: rd A(1,h0,k1)+B(1,k1) */ READ_A4A(aX, 1, 0, 1); READ_B4A(bO, 1, 1); \
    LGKM(8); BAR; PHI; MFMA16(1, aY, bE); PLO; \
  /* ph7: rd A(1,h1,k1) */ READ_A4A(aY, 1, 1, 1); \
    LGKM(4); VM0; BAR; PHI; MFMA16(0, aX, bO); PLO; \
  /* ph8: rd next A(0,h0,k0)+B(0,k0) */ \
    if (RD) { READ_A4A(aX, 0, 0, 0); READ_B4A(bE, 0, 0); } \
    if (SN) { STAGE_B(1, 0, (T0) + 192); STAGE_B(1, 1, (T0) + 192); } \
    if (RD) { LGKM(8); } else { LGKM(0); } \
    BAR; PHI; MFMA16(1, aY, bO); PLO; \
} while(0)

__global__ __launch_bounds__(512, 2)
void gemm_min8(const unsigned short* __restrict__ fA, const unsigned short* __restrict__ bB,
               const float* __restrict__ bn, uint32_t* __restrict__ minbits) {
  __shared__ unsigned short sA[2][2][8192];   // 64 KiB
  __shared__ unsigned short sB[2][2][8192];   // 64 KiB

  const int nwg = GRID2;
  int bid = blockIdx.x;
  const int qch = nwg >> 3, rch = nwg & 7;
  int xcd = bid & 7, loc = bid >> 3;
  int swz = (xcd < rch ? xcd * (qch + 1) : rch * (qch + 1) + (xcd - rch) * qch) + loc;
  int mt = swz % MT2;            // M-fast: consecutive blocks share the B (bank) panel
  int nt = swz / MT2;

  int tid = threadIdx.x;
  int lane = tid & 63, wave = tid >> 6;
  int wm = wave >> 2, wn = wave & 3, bq = wn & 1, bh = wn >> 1;
  int lr = lane & 15, lk8 = (lane >> 4) * 8;
  int lswz = (lane & 7) << 3;    // XOR on 16B-slot bits (ushort units)

  const unsigned short* gA = fA + (size_t)(mt * 256) * DIM;
  const unsigned short* gB = bB + (size_t)(nt * 256) * DIM;

  int srow = tid >> 3;                                    // 0..63
  int scol = ((tid & 7) * 8) ^ (((tid >> 3) & 7) << 3);   // pre-swizzled source col (bf16)
  int sdst = tid * 8;                                     // linear LDS dest (ushort)

  // 32-bit LDS byte-offset bases for asm ds_read (E: kk=0, O: kk=1)
  uint32_t aOffE = (uint32_t)(uintptr_t)(lds_us*)&sA[0][wm][lr * 64 + (lk8 ^ lswz)];
  uint32_t aOffO = (uint32_t)(uintptr_t)(lds_us*)&sA[0][wm][lr * 64 + ((32 + lk8) ^ lswz)];
  uint32_t bOffE = (uint32_t)(uintptr_t)(lds_us*)&sB[0][bh][(bq * 64 + lr) * 64 + (lk8 ^ lswz)];
  uint32_t bOffO = (uint32_t)(uintptr_t)(lds_us*)&sB[0][bh][(bq * 64 + lr) * 64 + ((32 + lk8) ^ lswz)];

  f32x4 acc[8][4] = {};
  f32x4 aX[4], aY[4], bE[4], bO[4];

  // prologue: tile0 -> buf0 (8 gll16); tile1 B -> buf1 (4 gll16);
  // gate own 8 (VM4), barrier (publish), then pre-read ph1's fragments.
  STAGE_A(0, 0, 0); STAGE_A(0, 1, 0);
  STAGE_B(0, 0, 0); STAGE_B(0, 1, 0);
  STAGE_B(1, 0, 64); STAGE_B(1, 1, 64);
  VM4; BAR;
  READ_A4A(aX, 0, 0, 0); READ_B4A(bE, 0, 0);   // drained by ph1's LGKM(4)

#pragma unroll 1
  for (int i = 0; i < NIT - 1; ++i) {
    ITER(i * 128, 1, 1);
  }
  ITER((NIT - 1) * 128, 0, 0);   // tiles 22,23: no next-tile stages/read-ahead

  // epilogue: per-row min over this tile's 256 columns of (bn - 2*dot)
  float bnv[4];
#pragma unroll
  for (int n_ = 0; n_ < 4; ++n_)
    bnv[n_] = bn[nt * 256 + wn * 64 + n_ * 16 + lr];
  int qbase = mt * 256 + wm * 128;
#pragma unroll
  for (int m_ = 0; m_ < 8; ++m_) {
#pragma unroll
    for (int r = 0; r < 4; ++r) {
      float v = bnv[0] - 2.0f * acc[m_][0][r];
      v = fminf(v, bnv[1] - 2.0f * acc[m_][1][r]);
      v = fminf(v, bnv[2] - 2.0f * acc[m_][2][r]);
      v = fminf(v, bnv[3] - 2.0f * acc[m_][3][r]);
      // C/D layout: col = lane&15, row = (lane>>4)*4 + r
      v = fminf(v, __shfl_xor(v, 1));
      v = fminf(v, __shfl_xor(v, 2));
      v = fminf(v, __shfl_xor(v, 4));
      v = fminf(v, __shfl_xor(v, 8));
      if (lr == 0) {
        int q = qbase + m_ * 16 + (lane >> 4) * 4 + r;
        atomicMin(&minbits[q], __float_as_uint(v));  // positive floats: uint order == float order
      }
    }
  }
}

// ---- patch scores + per-image max -------------------------------------
__global__ void scores_kernel(const uint32_t* __restrict__ minbits, const float* __restrict__ qn,
                              float* __restrict__ ps, float* __restrict__ img) {
  int q = blockIdx.x * 256 + threadIdx.x;
  if (q >= NQ) return;
  float s = __uint_as_float(minbits[q]) + qn[q];
  ps[q] = s;
  atomicMax((uint32_t*)&img[q / 784], __float_as_uint(s));  // scores > 0
}

// ---- bilinear 28x28 -> 224x224 (half-pixel centers, edge clamp) -------
__global__ void resize_kernel(const float* __restrict__ ps, float* __restrict__ masks) {
  int idx = blockIdx.x * 256 + threadIdx.x;
  if (idx >= NPIX) return;
  int b   = idx / (224 * 224);
  int rem = idx - b * (224 * 224);
  int oy  = rem / 224;
  int ox  = rem - oy * 224;
  float sy = (oy + 0.5f) * 0.125f - 0.5f;
  float sx = (ox + 0.5f) * 0.125f - 0.5f;
  float fy0 = floorf(sy), fx0 = floorf(sx);
  int y0 = (int)fy0, x0 = (int)fx0;
  float fy = sy - fy0, fx = sx - fx0;
  int y0c = min(max(y0, 0), 27),     y1c = min(max(y0 + 1, 0), 27);
  int x0c = min(max(x0, 0), 27),     x1c = min(max(x0 + 1, 0), 27);
  const float* p = ps + b * 784;
  float top = p[y0c * 28 + x0c] * (1.f - fx) + p[y0c * 28 + x1c] * fx;
  float bot = p[y1c * 28 + x0c] * (1.f - fx) + p[y1c * 28 + x1c] * fx;
  masks[idx] = top * (1.f - fy) + bot * fy;
}

// ---- host launch -------------------------------------------------------
extern "C" void kernel_launch(void* const* d_in, const int* in_sizes, int n_in,
                              void* d_out, int out_size, void* d_ws, size_t ws_size,
                              hipStream_t stream) {
  const float* features = (const float*)d_in[0];   // [6272, 1536]
  const float* bank     = (const float*)d_in[1];   // [50000, 1536]

  char* ws = (char*)d_ws;
  size_t off = 0;
  unsigned short* bankB = (unsigned short*)(ws + off); off += (size_t)NBP2 * DIM * 2;  // 154.1 MB
  unsigned short* featB = (unsigned short*)(ws + off); off += (size_t)NQP * DIM * 2;   // 19.7 MB
  float*    bn      = (float*)(ws + off);    off += (size_t)NBP2 * 4;
  float*    qn      = (float*)(ws + off);    off += (size_t)NQP * 4;
  uint32_t* minbits = (uint32_t*)(ws + off); off += (size_t)NQP * 4;
  float*    ps      = (float*)(ws + off);    off += (size_t)NQ * 4;

  float* out_scores = (float*)d_out;       // [8]
  float* masks      = out_scores + 8;      // [8,224,224]

  hipLaunchKernelGGL(init_kernel, dim3(25), dim3(256), 0, stream, minbits, out_scores);
  hipLaunchKernelGGL(conv_rows, dim3(NBP2 / 4), dim3(256), 0, stream, bank, bankB, bn, NB, NBP2);
  hipLaunchKernelGGL(conv_rows, dim3(NQP / 4), dim3(256), 0, stream, features, featB, qn, NQ, NQP);
  hipLaunchKernelGGL(gemm_min8, dim3(GRID2), dim3(512), 0, stream, featB, bankB, bn, minbits);
  hipLaunchKernelGGL(scores_kernel, dim3(25), dim3(256), 0, stream, minbits, qn, ps, out_scores);
  hipLaunchKernelGGL(resize_kernel, dim3((NPIX + 255) / 256), dim3(256), 0, stream, ps, masks);
}

// Round 13
// 728.547 us; speedup vs baseline: 1.3880x; 1.3134x over previous
//
#include <hip/hip_runtime.h>
#include <stdint.h>

// ---- Problem constants -------------------------------------------------
#define DIM   1536
#define NQ    6272      // 8 * 28 * 28 queries
#define NQP   6400      // padded to 25 * 256
#define NB    50000     // bank rows
#define NBP2  50176     // padded to 196 * 256
#define MT2   25
#define NT2   196
#define GRID2 (MT2 * NT2)
#define NKT   24        // 1536 / 64 K-tiles
#define NIT   12        // NKT / 2 iterations
#define NPIX  (8 * 224 * 224)

typedef float f32x4 __attribute__((ext_vector_type(4)));
typedef int   i32x4 __attribute__((ext_vector_type(4)));
typedef __attribute__((address_space(3))) signed char lds_i8;

__device__ inline void gll16(const signed char* g, signed char* l) {
  __builtin_amdgcn_global_load_lds(
      (const __attribute__((address_space(1))) uint32_t*)g,
      (__attribute__((address_space(3))) uint32_t*)l, 16, 0, 0);
}

// ---- init: minbits = +inf, image scores = 0 ---------------------------
__global__ void init_kernel(uint32_t* __restrict__ minbits, float* __restrict__ out_scores) {
  int i = blockIdx.x * 256 + threadIdx.x;
  if (i < NQP) minbits[i] = 0x7F800000u;   // +inf
  if (i < 8)   out_scores[i] = 0.0f;
}

// ---- fp32 -> int8 row quantization + fp32 row norms + scales ----------
// one wave per row; scale = maxabs/127; norm from ORIGINAL fp32 values.
__global__ void quant_rows(const float* __restrict__ src, signed char* __restrict__ dst,
                           float* __restrict__ norms, float* __restrict__ scales,
                           int nsrc, int ndst) {
  int row  = blockIdx.x * 4 + (threadIdx.x >> 6);
  int lane = threadIdx.x & 63;
  if (row >= ndst) return;
  uint32_t* drow = (uint32_t*)(dst + (size_t)row * DIM);
  if (row < nsrc) {
    const float4* s = (const float4*)(src + (size_t)row * DIM);
    float4 v[6]; float ns = 0.f, mx = 0.f;
#pragma unroll
    for (int i = 0; i < 6; ++i) {
      v[i] = s[lane + 64 * i];
      ns += v[i].x * v[i].x + v[i].y * v[i].y + v[i].z * v[i].z + v[i].w * v[i].w;
      mx = fmaxf(mx, fmaxf(fmaxf(fabsf(v[i].x), fabsf(v[i].y)),
                           fmaxf(fabsf(v[i].z), fabsf(v[i].w))));
    }
#pragma unroll
    for (int off = 32; off >= 1; off >>= 1) {
      ns += __shfl_xor(ns, off);
      mx = fmaxf(mx, __shfl_xor(mx, off));
    }
    float inv = (mx > 0.f) ? 127.0f / mx : 0.f;
#pragma unroll
    for (int i = 0; i < 6; ++i) {
      int a = max(-127, min(127, __float2int_rn(v[i].x * inv)));
      int b = max(-127, min(127, __float2int_rn(v[i].y * inv)));
      int c = max(-127, min(127, __float2int_rn(v[i].z * inv)));
      int d = max(-127, min(127, __float2int_rn(v[i].w * inv)));
      drow[lane + 64 * i] = (uint32_t)(a & 255) | ((uint32_t)(b & 255) << 8) |
                            ((uint32_t)(c & 255) << 16) | ((uint32_t)(d & 255) << 24);
    }
    if (lane == 0) { norms[row] = ns; scales[row] = mx * (1.0f / 127.0f); }
  } else {
#pragma unroll
    for (int i = 0; i < 6; ++i) drow[lane + 64 * i] = 0u;
    if (lane == 0) { norms[row] = 1e30f; scales[row] = 0.f; }   // pad never wins
  }
}

// ---- fused 256x256 int8 GEMM + column-min -----------------------------
// BM=BN=256, BK=64, 512 thr = 8 waves (2M x 4N), per-wave 128x64 out.
// mfma_i32_16x16x64_i8: K=64/instr -> 32 MFMA/tile/wave (half of bf16).
// i8 rows are 64B: a 16-row fragment = contiguous 1KB, lane->distinct 16B
// slot => conflict-free reads AND linear gll16 staging, no swizzle.
// R9 counted-lgkm skeleton: reads issued >=1 phase ahead, LGKM(n=just-
// issued) drains only older; gates (VM2) pre-barrier, reads post-barrier.
#define BAR   do { asm volatile("s_barrier" ::: "memory"); \
                   __builtin_amdgcn_sched_barrier(0); } while(0)
#define LGKM(n) do { asm volatile("s_waitcnt lgkmcnt(" #n ")" ::: "memory"); \
                     __builtin_amdgcn_sched_barrier(0); } while(0)
#define VM0   asm volatile("s_waitcnt vmcnt(0)" ::: "memory")
#define VM2   asm volatile("s_waitcnt vmcnt(2)" ::: "memory")
#define VM4   asm volatile("s_waitcnt vmcnt(4)" ::: "memory")
#define PHI   __builtin_amdgcn_s_setprio(1)
#define PLO   __builtin_amdgcn_s_setprio(0)

#define DSR(dst, base, imm) \
  asm volatile("ds_read_b128 %0, %1 offset:%2" : "=v"(dst) : "v"(base), "i"(imm))

// A quad: m-fragments quad*4..quad*4+3 (rows m*16+lr), full K=64 per b128
#define READ_AQ(dst, bufI, quad) do { \
  DSR(dst[0], aOff, (bufI) * 16384 + (quad) * 4096 + 0);    \
  DSR(dst[1], aOff, (bufI) * 16384 + (quad) * 4096 + 1024); \
  DSR(dst[2], aOff, (bufI) * 16384 + (quad) * 4096 + 2048); \
  DSR(dst[3], aOff, (bufI) * 16384 + (quad) * 4096 + 3072); \
} while(0)

// B quad: n-fragments 0..3 (rows bh*128+bq*64+n*16+lr), full K=64
#define READ_B4(dst, bufI) do { \
  DSR(dst[0], bOff, (bufI) * 16384 + 0);    \
  DSR(dst[1], bOff, (bufI) * 16384 + 1024); \
  DSR(dst[2], bOff, (bufI) * 16384 + 2048); \
  DSR(dst[3], bOff, (bufI) * 16384 + 3072); \
} while(0)

// 8 MFMA: m-pair (mb, mb+1) x 4 n, K=64
#define MFMA8(mb, x0, x1, b4) do { \
  _Pragma("unroll") for (int n_ = 0; n_ < 4; ++n_) { \
    acc[(mb)][n_]     = __builtin_amdgcn_mfma_i32_16x16x64_i8( \
      __builtin_bit_cast(i32x4, (x0)), __builtin_bit_cast(i32x4, b4[n_]), acc[(mb)][n_], 0, 0, 0); \
    acc[(mb) + 1][n_] = __builtin_amdgcn_mfma_i32_16x16x64_i8( \
      __builtin_bit_cast(i32x4, (x1)), __builtin_bit_cast(i32x4, b4[n_]), acc[(mb) + 1][n_], 0, 0, 0); \
  } \
} while(0)

// stage one 256x64 i8 tile (16 KB) = 2 gll16/thread; all linear
#define STAGE_A(bufI, ktc) do { \
  const signed char* _g = gA + (size_t)srow * DIM + (ktc) + scol; \
  gll16(_g,                      &sA[bufI][sdst]); \
  gll16(_g + (size_t)128 * DIM,  &sA[bufI][8192 + sdst]); \
} while(0)

#define STAGE_B(bufI, ktc) do { \
  const signed char* _g = gB + (size_t)srow * DIM + (ktc) + scol; \
  gll16(_g,                      &sB[bufI][sdst]); \
  gll16(_g + (size_t)128 * DIM,  &sB[bufI][8192 + sdst]); \
} while(0)

// iter i: tiles t0=2i (buf0, ph1-4) + t1 (buf1, ph5-8); T0 = i*128 (cols).
// Reads: ph1 aQ(buf0,q1); ph3 aP(buf1,q0)+bO(buf1); ph5 aQ(buf1,q1);
//        ph7 aP(buf0',q0)+bE(buf0')  [next tiles].
// Stages: ph2 B(t2), ph4 A(t2), ph6 B(t3), ph8 A(t3).
// Gates: ph2 VM2 (keeps own stage, retires t1's A+B -> ph3 reads safe);
//        ph6 VM2 (retires t2's A+B -> ph7 reads safe). Stage->gate->BAR.
// WAR: every staged region's readers drained at an earlier phase's LGKM
// + barrier (verified per-slot). Tail: VM0 at ph2, LGKM(0) at ph7.
#define ITER(T0, SN, RD) do { \
  /* ph1 */ READ_AQ(aQ, 0, 1); \
    LGKM(4); BAR; PHI; MFMA8(0, aP[0], aP[1], bE); PLO; \
  /* ph2 */ if (SN) { STAGE_B(0, (T0) + 128); VM2; } else { VM0; } \
    BAR; PHI; MFMA8(2, aP[2], aP[3], bE); PLO; \
  /* ph3 */ READ_AQ(aP, 1, 0); READ_B4(bO, 1); \
    LGKM(8); BAR; PHI; MFMA8(4, aQ[0], aQ[1], bE); PLO; \
  /* ph4 */ if (SN) STAGE_A(0, (T0) + 128); \
    BAR; PHI; MFMA8(6, aQ[2], aQ[3], bE); PLO; \
  /* ph5 */ READ_AQ(aQ, 1, 1); \
    LGKM(4); BAR; PHI; MFMA8(0, aP[0], aP[1], bO); PLO; \
  /* ph6 */ if (SN) { STAGE_B(1, (T0) + 192); VM2; } \
    BAR; PHI; MFMA8(2, aP[2], aP[3], bO); PLO; \
  /* ph7 */ if (RD) { READ_AQ(aP, 0, 0); READ_B4(bE, 0); LGKM(8); } else { LGKM(0); } \
    BAR; PHI; MFMA8(4, aQ[0], aQ[1], bO); PLO; \
  /* ph8 */ if (SN) STAGE_A(1, (T0) + 192); \
    BAR; PHI; MFMA8(6, aQ[2], aQ[3], bO); PLO; \
} while(0)

__global__ __launch_bounds__(512, 2)
void gemm_min8(const signed char* __restrict__ fA, const signed char* __restrict__ bB,
               const float* __restrict__ bn, const float* __restrict__ bscale,
               const float* __restrict__ qscale, uint32_t* __restrict__ minbits) {
  __shared__ __align__(16) signed char sA[2][16384];   // [buf][256 rows][64] = 32 KiB
  __shared__ __align__(16) signed char sB[2][16384];   // 32 KiB

  const int nwg = GRID2;
  int bid = blockIdx.x;
  const int qch = nwg >> 3, rch = nwg & 7;
  int xcd = bid & 7, loc = bid >> 3;
  int swz = (xcd < rch ? xcd * (qch + 1) : rch * (qch + 1) + (xcd - rch) * qch) + loc;
  int mt = swz % MT2;            // M-fast: consecutive blocks share the B (bank) panel
  int nt = swz / MT2;

  int tid = threadIdx.x;
  int lane = tid & 63, wave = tid >> 6;
  int wm = wave >> 2, wn = wave & 3, bq = wn & 1, bh = wn >> 1;
  int lr = lane & 15, k16 = lane >> 4;

  const signed char* gA = fA + (size_t)(mt * 256) * DIM;
  const signed char* gB = bB + (size_t)(nt * 256) * DIM;

  int srow = tid >> 2;           // 0..127
  int scol = (tid & 3) * 16;     // i8 units
  int sdst = tid * 16;           // byte offset in 8 KB half

  // LDS byte-offset read bases; fragment/buffer offsets are immediates
  uint32_t aOff = (uint32_t)(uintptr_t)(lds_i8*)&sA[0][(wm * 128 + lr) * 64 + k16 * 16];
  uint32_t bOff = (uint32_t)(uintptr_t)(lds_i8*)&sB[0][(bh * 128 + bq * 64 + lr) * 64 + k16 * 16];

  i32x4 acc[8][4] = {};
  f32x4 aP[4], aQ[4], bE[4], bO[4];

  // prologue: tiles 0 (buf0) + 1 (buf1) staged; retire tile0 (VM4 keeps
  // tile1's 4 in flight, gated at first ph2); publish; pre-read ph1 frags.
  STAGE_A(0, 0); STAGE_B(0, 0);
  STAGE_A(1, 64); STAGE_B(1, 64);
  VM4; BAR;
  READ_AQ(aP, 0, 0); READ_B4(bE, 0);   // drained by ph1's LGKM(4)

#pragma unroll 1
  for (int i = 0; i < NIT - 1; ++i) {
    ITER(i * 128, 1, 1);
  }
  ITER((NIT - 1) * 128, 0, 0);   // tiles 22,23: no stages/read-ahead

  // epilogue: per-row min over this tile's 256 cols of (bn - 2*sq*sb*idot)
  float bnv[4], bsv[4];
#pragma unroll
  for (int n_ = 0; n_ < 4; ++n_) {
    int col = nt * 256 + wn * 64 + n_ * 16 + lr;
    bnv[n_] = bn[col];
    bsv[n_] = 2.0f * bscale[col];
  }
  int qbase = mt * 256 + wm * 128;
#pragma unroll
  for (int m_ = 0; m_ < 8; ++m_) {
    f32x4 sq = *(const f32x4*)&qscale[qbase + m_ * 16 + (lane >> 4) * 4];
#pragma unroll
    for (int r = 0; r < 4; ++r) {
      float sqr = sq[r];
      float v =          bnv[0] - bsv[0] * sqr * (float)acc[m_][0][r];
      v = fminf(v, bnv[1] - bsv[1] * sqr * (float)acc[m_][1][r]);
      v = fminf(v, bnv[2] - bsv[2] * sqr * (float)acc[m_][2][r]);
      v = fminf(v, bnv[3] - bsv[3] * sqr * (float)acc[m_][3][r]);
      // C/D layout (shape-determined): col = lane&15, row = (lane>>4)*4+r
      v = fminf(v, __shfl_xor(v, 1));
      v = fminf(v, __shfl_xor(v, 2));
      v = fminf(v, __shfl_xor(v, 4));
      v = fminf(v, __shfl_xor(v, 8));
      if (lr == 0) {
        int q = qbase + m_ * 16 + (lane >> 4) * 4 + r;
        atomicMin(&minbits[q], __float_as_uint(v));  // positive floats: uint order == float order
      }
    }
  }
}

// ---- patch scores + per-image max -------------------------------------
__global__ void scores_kernel(const uint32_t* __restrict__ minbits, const float* __restrict__ qn,
                              float* __restrict__ ps, float* __restrict__ img) {
  int q = blockIdx.x * 256 + threadIdx.x;
  if (q >= NQ) return;
  float s = __uint_as_float(minbits[q]) + qn[q];
  ps[q] = s;
  atomicMax((uint32_t*)&img[q / 784], __float_as_uint(s));  // scores > 0
}

// ---- bilinear 28x28 -> 224x224 (half-pixel centers, edge clamp) -------
__global__ void resize_kernel(const float* __restrict__ ps, float* __restrict__ masks) {
  int idx = blockIdx.x * 256 + threadIdx.x;
  if (idx >= NPIX) return;
  int b   = idx / (224 * 224);
  int rem = idx - b * (224 * 224);
  int oy  = rem / 224;
  int ox  = rem - oy * 224;
  float sy = (oy + 0.5f) * 0.125f - 0.5f;
  float sx = (ox + 0.5f) * 0.125f - 0.5f;
  float fy0 = floorf(sy), fx0 = floorf(sx);
  int y0 = (int)fy0, x0 = (int)fx0;
  float fy = sy - fy0, fx = sx - fx0;
  int y0c = min(max(y0, 0), 27),     y1c = min(max(y0 + 1, 0), 27);
  int x0c = min(max(x0, 0), 27),     x1c = min(max(x0 + 1, 0), 27);
  const float* p = ps + b * 784;
  float top = p[y0c * 28 + x0c] * (1.f - fx) + p[y0c * 28 + x1c] * fx;
  float bot = p[y1c * 28 + x0c] * (1.f - fx) + p[y1c * 28 + x1c] * fx;
  masks[idx] = top * (1.f - fy) + bot * fy;
}

// ---- host launch -------------------------------------------------------
extern "C" void kernel_launch(void* const* d_in, const int* in_sizes, int n_in,
                              void* d_out, int out_size, void* d_ws, size_t ws_size,
                              hipStream_t stream) {
  const float* features = (const float*)d_in[0];   // [6272, 1536]
  const float* bank     = (const float*)d_in[1];   // [50000, 1536]

  char* ws = (char*)d_ws;
  size_t off = 0;
  signed char* bankQ = (signed char*)(ws + off); off += (size_t)NBP2 * DIM;   // 77.1 MB
  signed char* featQ = (signed char*)(ws + off); off += (size_t)NQP * DIM;    //  9.8 MB
  float*    bn      = (float*)(ws + off);    off += (size_t)NBP2 * 4;
  float*    qn      = (float*)(ws + off);    off += (size_t)NQP * 4;
  float*    bscale  = (float*)(ws + off);    off += (size_t)NBP2 * 4;
  float*    qscale  = (float*)(ws + off);    off += (size_t)NQP * 4;
  uint32_t* minbits = (uint32_t*)(ws + off); off += (size_t)NQP * 4;
  float*    ps      = (float*)(ws + off);    off += (size_t)NQ * 4;

  float* out_scores = (float*)d_out;       // [8]
  float* masks      = out_scores + 8;      // [8,224,224]

  hipLaunchKernelGGL(init_kernel, dim3(25), dim3(256), 0, stream, minbits, out_scores);
  hipLaunchKernelGGL(quant_rows, dim3(NBP2 / 4), dim3(256), 0, stream, bank, bankQ, bn, bscale, NB, NBP2);
  hipLaunchKernelGGL(quant_rows, dim3(NQP / 4), dim3(256), 0, stream, features, featQ, qn, qscale, NQ, NQP);
  hipLaunchKernelGGL(gemm_min8, dim3(GRID2), dim3(512), 0, stream, featQ, bankQ, bn, bscale, qscale, minbits);
  hipLaunchKernelGGL(scores_kernel, dim3(25), dim3(256), 0, stream, minbits, qn, ps, out_scores);
  hipLaunchKernelGGL(resize_kernel, dim3((NPIX + 255) / 256), dim3(256), 0, stream, ps, masks);
}